// Round 1
// baseline (5655.558 us; speedup 1.0000x reference)
//
#include <hip/hip_runtime.h>
#include <hip/hip_bf16.h>
#include <stdint.h>

// ---------------- problem constants ----------------
#define T_SEQ  2000
#define IN_DIM 13
#define HID    128
#define NB     16           // batch rows per block
#define NBLK   32           // 512 / NB
#define NTHR   512          // 8 waves

// ---------------- LDS geometry ----------------
// hA: [2 parity][16 rows][192 cols bf16]; row = [h_a(0..127) | x(128..140) | 1.0(141) | 0]
// hB: [2 parity][16 rows][128 cols bf16]
// byte column XOR-swizzled by ((row&7)<<4) to kill bank conflicts on ds_read_b128.
#define HA_STRIDE 384
#define HA_BUF    (NB * HA_STRIDE)           // 6144
#define HB_STRIDE 256
#define HB_BUF    (NB * HB_STRIDE)           // 4096
#define HB_BASE   (2 * HA_BUF)               // 12288
#define LDS_BYTES (2 * HA_BUF + 2 * HB_BUF)  // 20480

typedef __bf16 bf16x8 __attribute__((ext_vector_type(8)));
typedef float  f32x4  __attribute__((ext_vector_type(4)));

__device__ __forceinline__ uint16_t f2bf(float f) {
    union { float f; uint32_t u; } v; v.f = f;
    return (uint16_t)((v.u + 0x7FFFu + ((v.u >> 16) & 1u)) >> 16);  // RNE
}
__device__ __forceinline__ float bf2f(uint16_t b) {
    union { uint32_t u; float f; } v; v.u = ((uint32_t)b) << 16; return v.f;
}
__device__ __forceinline__ float bflo(uint32_t u){ union{uint32_t u;float f;}v; v.u = u<<16;          return v.f; }
__device__ __forceinline__ float bfhi(uint32_t u){ union{uint32_t u;float f;}v; v.u = u & 0xFFFF0000u; return v.f; }

#define LOG2E 1.44269504088896340736f
#define TLOG2E 2.88539008177792681472f

__global__ __launch_bounds__(NTHR, 1)
void lstm2_kernel(const float* __restrict__ x,
                  const float* __restrict__ Wih0, const float* __restrict__ Whh0,
                  const float* __restrict__ bih0, const float* __restrict__ bhh0,
                  const float* __restrict__ Wih1, const float* __restrict__ Whh1,
                  const float* __restrict__ bih1, const float* __restrict__ bhh1,
                  const float* __restrict__ Wfc,  const float* __restrict__ bfc,
                  float* __restrict__ out)
{
    __shared__ alignas(16) unsigned char lds[LDS_BYTES];

    const int tid  = threadIdx.x;
    const int lane = tid & 63;
    const int wv   = tid >> 6;     // wave 0..7
    const int ln   = lane & 15;    // batch col (B-frag) / weight row-in-tile (A-frag)
    const int lhi  = lane >> 4;    // k-group 0..3
    const int bs0  = blockIdx.x * NB;

    // ---- zero LDS ----
    for (int i = tid; i < LDS_BYTES/4; i += NTHR) ((uint32_t*)lds)[i] = 0u;
    __syncthreads();

    // constant 1.0 at col 141 (bias slot), both parities
    if (tid < 2*NB) {
        int p = tid >> 4, n = tid & 15;
        int off = p*HA_BUF + n*HA_STRIDE + (282 ^ ((n & 7) << 4));
        *(uint16_t*)(lds + off) = 0x3F80u;
    }
    // x~(t=0) into parity 0
    if (tid < 256) {
        int b = tid >> 4, i = tid & 15;
        if (i < IN_DIM) {
            float xv = x[((size_t)(bs0 + b) * T_SEQ + 0) * IN_DIM + i];
            int off = b*HA_STRIDE + ((2*(128 + i)) ^ ((b & 7) << 4));
            *(uint16_t*)(lds + off) = f2bf(xv);
        }
    }

    // ---- register-resident weight fragments (A-operand: gates-as-M) ----
    // wave wv owns gate tiles {wv, wv+8, wv+16, wv+24} == gate types {i,f,g,o}
    bf16x8 wA0[4][5];    // L0: kk 0..3 = Whh0, kk 4 = [Wih0 | bias0 | 0]
    bf16x8 wA1[4][8];    // L1: kk 0..3 = Wih1, kk 4..7 = Whh1
    uint32_t b1p[4][2];  // L1 bias, packed bf16 pairs
    #pragma unroll
    for (int t4 = 0; t4 < 4; ++t4) {
        const int grow = (wv + 8*t4) * 16 + ln;
        #pragma unroll
        for (int kk = 0; kk < 4; ++kk) {
            const float* s = Whh0 + (size_t)grow * HID + kk*32 + lhi*8;
            #pragma unroll
            for (int j = 0; j < 8; ++j) wA0[t4][kk][j] = (__bf16)s[j];
        }
        {
            const int c0 = lhi * 8;
            #pragma unroll
            for (int j = 0; j < 8; ++j) {
                const int c = c0 + j;
                float v = 0.0f;
                if (c < IN_DIM)       v = Wih0[(size_t)grow * IN_DIM + c];
                else if (c == IN_DIM) v = bih0[grow] + bhh0[grow];
                wA0[t4][4][j] = (__bf16)v;
            }
        }
        #pragma unroll
        for (int kk = 0; kk < 4; ++kk) {
            const float* s = Wih1 + (size_t)grow * HID + kk*32 + lhi*8;
            #pragma unroll
            for (int j = 0; j < 8; ++j) wA1[t4][kk][j] = (__bf16)s[j];
        }
        #pragma unroll
        for (int kk = 0; kk < 4; ++kk) {
            const float* s = Whh1 + (size_t)grow * HID + kk*32 + lhi*8;
            #pragma unroll
            for (int j = 0; j < 8; ++j) wA1[t4][4+kk][j] = (__bf16)s[j];
        }
        const int g0 = (wv + 8*t4) * 16 + lhi*4;
        b1p[t4][0] = (uint32_t)f2bf(bih1[g0+0] + bhh1[g0+0])
                   | ((uint32_t)f2bf(bih1[g0+1] + bhh1[g0+1]) << 16);
        b1p[t4][1] = (uint32_t)f2bf(bih1[g0+2] + bhh1[g0+2])
                   | ((uint32_t)f2bf(bih1[g0+3] + bhh1[g0+3]) << 16);
    }

    f32x4 cA = {0.f,0.f,0.f,0.f};      // layer-0 cell state (units u0..u0+3)
    f32x4 cB = {0.f,0.f,0.f,0.f};      // layer-1 cell state
    const int sw  = (ln & 7) << 4;     // read/write swizzle for this lane's row
    const int k2w = 2 * (wv*16 + lhi*4);   // byte col of this lane's 4 h-values

    __syncthreads();

    for (int t = 0; t < T_SEQ; ++t) {
        const int p   = t & 1;
        const int haR = p ? HA_BUF : 0;
        const int haW = p ? 0 : HA_BUF;
        const int hbR = HB_BASE + (p ? HB_BUF : 0);
        const int hbW = HB_BASE + (p ? 0 : HB_BUF);

        // prefetch x(t+1) (latency hides under this step's compute)
        float xpre = 0.0f;
        {
            const int b = tid >> 4, i = tid & 15;
            if (tid < 256 && i < IN_DIM) {
                int tt = t + 1; if (tt >= T_SEQ) tt = T_SEQ - 1;
                xpre = x[((size_t)(bs0 + b) * T_SEQ + tt) * IN_DIM + i];
            }
        }

        // ================= layer 0 =================
        f32x4 acc[4];
        #pragma unroll
        for (int t4 = 0; t4 < 4; ++t4) { acc[t4][0]=0.f; acc[t4][1]=0.f; acc[t4][2]=0.f; acc[t4][3]=0.f; }
        {
            const int rbase = haR + ln * HA_STRIDE;
            #pragma unroll
            for (int kk = 0; kk < 5; ++kk) {
                const int off = rbase + ((kk*64 + lhi*16) ^ sw);
                bf16x8 bfr = *(const bf16x8*)(lds + off);
                #pragma unroll
                for (int t4 = 0; t4 < 4; ++t4)
                    acc[t4] = __builtin_amdgcn_mfma_f32_16x16x32_bf16(wA0[t4][kk], bfr, acc[t4], 0, 0, 0);
            }
        }
        uint32_t hpk0, hpk1;
        {
            float hv[4];
            #pragma unroll
            for (int r = 0; r < 4; ++r) {
                const float gi = acc[0][r], gf = acc[1][r], gg = acc[2][r], go = acc[3][r];
                const float ei = __builtin_amdgcn_exp2f(-LOG2E * gi);
                const float eg = __builtin_amdgcn_exp2f( TLOG2E * gg);
                const float ig = (eg - 1.0f) * __builtin_amdgcn_rcpf((1.0f + ei) * (1.0f + eg)); // sig(gi)*tanh(gg)
                const float ff = __builtin_amdgcn_rcpf(1.0f + __builtin_amdgcn_exp2f(-LOG2E * gf));
                const float c  = ff * cA[r] + ig;
                cA[r] = c;
                const float eo = __builtin_amdgcn_exp2f(-LOG2E * go);
                const float ec = __builtin_amdgcn_exp2f( TLOG2E * c);
                hv[r] = (ec - 1.0f) * __builtin_amdgcn_rcpf((1.0f + eo) * (1.0f + ec));          // sig(go)*tanh(c)
            }
            hpk0 = (uint32_t)f2bf(hv[0]) | ((uint32_t)f2bf(hv[1]) << 16);
            hpk1 = (uint32_t)f2bf(hv[2]) | ((uint32_t)f2bf(hv[3]) << 16);
        }
        {
            const int off = haW + ln * HA_STRIDE + (k2w ^ sw);
            *(uint32_t*)(lds + off)     = hpk0;
            *(uint32_t*)(lds + off + 4) = hpk1;
        }
        __syncthreads();   // h_a(t) visible

        // ================= layer 1 =================
        #pragma unroll
        for (int t4 = 0; t4 < 4; ++t4) {
            acc[t4][0] = bflo(b1p[t4][0]); acc[t4][1] = bfhi(b1p[t4][0]);
            acc[t4][2] = bflo(b1p[t4][1]); acc[t4][3] = bfhi(b1p[t4][1]);
        }
        {
            const int rbA = haW + ln * HA_STRIDE;   // h_a(t) : input projection
            #pragma unroll
            for (int kk = 0; kk < 4; ++kk) {
                const int off = rbA + ((kk*64 + lhi*16) ^ sw);
                bf16x8 bfr = *(const bf16x8*)(lds + off);
                #pragma unroll
                for (int t4 = 0; t4 < 4; ++t4)
                    acc[t4] = __builtin_amdgcn_mfma_f32_16x16x32_bf16(wA1[t4][kk], bfr, acc[t4], 0, 0, 0);
            }
            const int rbB = hbR + ln * HB_STRIDE;   // h_b(t-1) : recurrence
            #pragma unroll
            for (int kk = 0; kk < 4; ++kk) {
                const int off = rbB + ((kk*64 + lhi*16) ^ sw);
                bf16x8 bfr = *(const bf16x8*)(lds + off);
                #pragma unroll
                for (int t4 = 0; t4 < 4; ++t4)
                    acc[t4] = __builtin_amdgcn_mfma_f32_16x16x32_bf16(wA1[t4][4+kk], bfr, acc[t4], 0, 0, 0);
            }
        }
        {
            float hv[4];
            #pragma unroll
            for (int r = 0; r < 4; ++r) {
                const float gi = acc[0][r], gf = acc[1][r], gg = acc[2][r], go = acc[3][r];
                const float ei = __builtin_amdgcn_exp2f(-LOG2E * gi);
                const float eg = __builtin_amdgcn_exp2f( TLOG2E * gg);
                const float ig = (eg - 1.0f) * __builtin_amdgcn_rcpf((1.0f + ei) * (1.0f + eg));
                const float ff = __builtin_amdgcn_rcpf(1.0f + __builtin_amdgcn_exp2f(-LOG2E * gf));
                const float c  = ff * cB[r] + ig;
                cB[r] = c;
                const float eo = __builtin_amdgcn_exp2f(-LOG2E * go);
                const float ec = __builtin_amdgcn_exp2f( TLOG2E * c);
                hv[r] = (ec - 1.0f) * __builtin_amdgcn_rcpf((1.0f + eo) * (1.0f + ec));
            }
            const uint32_t q0 = (uint32_t)f2bf(hv[0]) | ((uint32_t)f2bf(hv[1]) << 16);
            const uint32_t q1 = (uint32_t)f2bf(hv[2]) | ((uint32_t)f2bf(hv[3]) << 16);
            const int off = hbW + ln * HB_STRIDE + (k2w ^ sw);
            *(uint32_t*)(lds + off)     = q0;
            *(uint32_t*)(lds + off + 4) = q1;
        }
        // stash x~(t+1) into next step's read buffer (cols 128.. ; disjoint from h reads/writes)
        if (tid < 256) {
            const int b = tid >> 4, i = tid & 15;
            if (i < IN_DIM) {
                const int off = haW + b * HA_STRIDE + ((2*(128+i)) ^ ((b & 7) << 4));
                *(uint16_t*)(lds + off) = f2bf(xpre);
            }
        }
        __syncthreads();   // h_b(t), x~(t+1) visible; safe to overwrite old buffers
    }

    // ---- epilogue: out = h_b(T-1) @ Wfc^T + bfc ; final h_b is in hB parity 0 ----
    if (tid < 64) {
        const int b = tid >> 2, c = tid & 3;
        float s = bfc[c];
        const float* wf = Wfc + (size_t)c * HID;
        const int rowoff = HB_BASE + b * HB_STRIDE;
        const int swb = (b & 7) << 4;
        #pragma unroll 8
        for (int k = 0; k < HID; ++k) {
            const uint16_t hb = *(const uint16_t*)(lds + rowoff + ((2*k) ^ swb));
            s += bf2f(hb) * wf[k];
        }
        out[(size_t)(bs0 + b) * 4 + c] = s;
    }
}

extern "C" void kernel_launch(void* const* d_in, const int* in_sizes, int n_in,
                              void* d_out, int out_size, void* d_ws, size_t ws_size,
                              hipStream_t stream) {
    const float* x    = (const float*)d_in[0];
    const float* Wih0 = (const float*)d_in[1];
    const float* Whh0 = (const float*)d_in[2];
    const float* bih0 = (const float*)d_in[3];
    const float* bhh0 = (const float*)d_in[4];
    const float* Wih1 = (const float*)d_in[5];
    const float* Whh1 = (const float*)d_in[6];
    const float* bih1 = (const float*)d_in[7];
    const float* bhh1 = (const float*)d_in[8];
    const float* Wfc  = (const float*)d_in[9];
    const float* bfc  = (const float*)d_in[10];
    (void)in_sizes; (void)n_in; (void)d_ws; (void)ws_size; (void)out_size;

    hipLaunchKernelGGL(lstm2_kernel, dim3(NBLK), dim3(NTHR), 0, stream,
                       x, Wih0, Whh0, bih0, bhh0, Wih1, Whh1, bih1, bhh1, Wfc, bfc,
                       (float*)d_out);
}

// Round 3
// 5300.286 us; speedup vs baseline: 1.0670x; 1.0670x over previous
//
#include <hip/hip_runtime.h>
#include <hip/hip_bf16.h>
#include <stdint.h>

// ---------------- problem constants ----------------
#define T_SEQ  2000
#define IN_DIM 13
#define HID    128
#define NB     16           // batch rows per block
#define NBLK   32           // 512 / NB
#define NTHR   256          // 4 waves -> 1 wave/SIMD -> 512-VGPR budget

// ---------------- LDS geometry ----------------
// hA: [2 parity][16 rows][192 cols bf16]; row = [h_a(0..127) | x(128..140) | 1.0(141) | 0]
// hB: [2 parity][16 rows][128 cols bf16]
// XB: L1 bias, f32x4 per (wv,g,q,lhi), uniform-address broadcast reads
// XZ: 16B of permanent zeros (masked xaug reads for lanes lhi>=2)
// XA: L0 x-augmented weight frags [wv][g][q][ln][lhi] (lhi<2 nonzero)
#define HA_STRIDE 384
#define HA_BUF    (NB * HA_STRIDE)           // 6144
#define HB_STRIDE 256
#define HB_BUF    (NB * HB_STRIDE)           // 4096
#define HB_BASE   (2 * HA_BUF)               // 12288
#define XB_BASE   (HB_BASE + 2 * HB_BUF)     // 20480
#define XZ_OFF    (XB_BASE + 2048)           // 22528
#define XA_BASE   24576
#define LDS_BYTES (XA_BASE + 32768)          // 57344
#define ZERO_W    ((XZ_OFF + 16) / 4)        // words to memset (hA,hB,XB,XZ)

typedef __bf16 bf16x8 __attribute__((ext_vector_type(8)));
typedef float  f32x4  __attribute__((ext_vector_type(4)));

__device__ __forceinline__ uint16_t f2bf(float f) {
    union { float f; uint32_t u; } v; v.f = f;
    return (uint16_t)((v.u + 0x7FFFu + ((v.u >> 16) & 1u)) >> 16);  // RNE
}
__device__ __forceinline__ float bf2f(uint16_t b) {
    union { uint32_t u; float f; } v; v.u = ((uint32_t)b) << 16; return v.f;
}

#define LOG2E 1.44269504088896340736f
#define TLOG2E 2.88539008177792681472f

__global__ __launch_bounds__(NTHR, 1)
void lstm2_kernel(const float* __restrict__ x,
                  const float* __restrict__ Wih0, const float* __restrict__ Whh0,
                  const float* __restrict__ bih0, const float* __restrict__ bhh0,
                  const float* __restrict__ Wih1, const float* __restrict__ Whh1,
                  const float* __restrict__ bih1, const float* __restrict__ bhh1,
                  const float* __restrict__ Wfc,  const float* __restrict__ bfc,
                  float* __restrict__ out)
{
    __shared__ alignas(16) unsigned char lds[LDS_BYTES];

    const int tid  = threadIdx.x;
    const int lane = tid & 63;
    const int wv   = tid >> 6;     // wave 0..3
    const int ln   = lane & 15;    // batch col (B-frag) / weight row-in-tile (A-frag)
    const int lhi  = lane >> 4;    // k-group 0..3
    const int bs0  = blockIdx.x * NB;

    // ---- zero the dynamic LDS region ----
    for (int i = tid; i < ZERO_W; i += NTHR) ((uint32_t*)lds)[i] = 0u;
    __syncthreads();

    // constant 1.0 at col 141 (bias slot of the x-augmented block), both parities
    if (tid < 2*NB) {
        int p = tid >> 4, n = tid & 15;
        int off = p*HA_BUF + n*HA_STRIDE + (282 ^ ((n & 7) << 4));
        *(uint16_t*)(lds + off) = 0x3F80u;
    }
    // x~(t=0) into hA parity 1 (phase 0 reads hA[1])
    {
        int b = tid >> 4, i = tid & 15;
        if (i < IN_DIM) {
            float xv = x[((size_t)(bs0 + b) * T_SEQ + 0) * IN_DIM + i];
            int off = HA_BUF + b*HA_STRIDE + ((2*(128 + i)) ^ ((b & 7) << 4));
            *(uint16_t*)(lds + off) = f2bf(xv);
        }
    }
    // L1 bias into XB: f32x4 per (wv,g,q,lhi), written by ln==0 lanes
    if (ln == 0) {
        #pragma unroll
        for (int g = 0; g < 4; ++g)
            #pragma unroll
            for (int q = 0; q < 2; ++q) {
                const int g0 = (8*g + wv + 4*q) * 16 + lhi*4;
                f32x4 bv;
                #pragma unroll
                for (int r = 0; r < 4; ++r) bv[r] = bih1[g0+r] + bhh1[g0+r];
                *(f32x4*)(lds + XB_BASE + (((wv*8 + g*2 + q)*4 + lhi) << 4)) = bv;
            }
    }
    // L0 x-augmented weight frags into XA ([Wih0 | bias0 | 0...], bf16)
    {
        const int myoff = (ln*64 + lhi*16) ^ ((ln & 7) << 4);
        #pragma unroll
        for (int g = 0; g < 4; ++g)
            #pragma unroll
            for (int q = 0; q < 2; ++q) {
                const int grow = (8*g + wv + 4*q) * 16 + ln;
                union { __bf16 h[8]; uint4 u4; } fr;
                const int c0 = lhi * 8;
                #pragma unroll
                for (int j = 0; j < 8; ++j) {
                    const int c = c0 + j;
                    float v = 0.0f;
                    if (c < IN_DIM)       v = Wih0[(size_t)grow * IN_DIM + c];
                    else if (c == IN_DIM) v = bih0[grow] + bhh0[grow];
                    fr.h[j] = (__bf16)v;
                }
                *(uint4*)(lds + XA_BASE + ((wv*8 + g*2 + q) << 10) + myoff) = fr.u4;
            }
    }

    // ---- register-resident weight fragments (A-operand: gates-as-M) ----
    // wave wv owns, per gate g and sub-tile q, gate-tile (8g + wv + 4q)
    bf16x8 wA0[4][2][4];   // L0: Whh0
    bf16x8 wA1[4][2][8];   // L1: kk 0..3 = Wih1, kk 4..7 = Whh1
    #pragma unroll
    for (int g = 0; g < 4; ++g) {
        #pragma unroll
        for (int q = 0; q < 2; ++q) {
            const int grow = (8*g + wv + 4*q) * 16 + ln;
            #pragma unroll
            for (int kk = 0; kk < 4; ++kk) {
                const float* s = Whh0 + (size_t)grow * HID + kk*32 + lhi*8;
                #pragma unroll
                for (int j = 0; j < 8; ++j) wA0[g][q][kk][j] = (__bf16)s[j];
            }
            #pragma unroll
            for (int kk = 0; kk < 4; ++kk) {
                const float* s = Wih1 + (size_t)grow * HID + kk*32 + lhi*8;
                #pragma unroll
                for (int j = 0; j < 8; ++j) wA1[g][q][kk][j] = (__bf16)s[j];
            }
            #pragma unroll
            for (int kk = 0; kk < 4; ++kk) {
                const float* s = Whh1 + (size_t)grow * HID + kk*32 + lhi*8;
                #pragma unroll
                for (int j = 0; j < 8; ++j) wA1[g][q][4+kk][j] = (__bf16)s[j];
            }
        }
    }

    f32x4 cA[2]; cA[0] = f32x4{0.f,0.f,0.f,0.f}; cA[1] = f32x4{0.f,0.f,0.f,0.f};
    f32x4 cB[2]; cB[0] = f32x4{0.f,0.f,0.f,0.f}; cB[1] = f32x4{0.f,0.f,0.f,0.f};
    const int sw = (ln & 7) << 4;      // read/write swizzle for this lane's row

    // loop-invariant addresses for the JIT xaug reads (zero-slot for lhi>=2)
    const int xslot = (lhi < 2) ? (XA_BASE + (wv << 13) + ((ln*64 + lhi*16) ^ sw))
                                : XZ_OFF;
    const int xmask = (lhi < 2) ? ~0 : 0;
    const int xbb   = XB_BASE + (((wv*8)*4 + lhi) << 4);   // + (g*2+q)*64

    // nonlinearity + pack + LDS write for one layer (both q sub-tiles)
    auto nlw = [&](f32x4 (&ac)[4][2], f32x4 (&cs)[2], int wbuf, int stride) {
        #pragma unroll
        for (int q = 0; q < 2; ++q) {
            union { __bf16 h[4]; uint2 u2; } pk;
            #pragma unroll
            for (int r = 0; r < 4; ++r) {
                const float gi = ac[0][q][r], gf = ac[1][q][r], gg = ac[2][q][r], go = ac[3][q][r];
                const float ei = __builtin_amdgcn_exp2f(-LOG2E * gi);
                const float eg = __builtin_amdgcn_exp2f( TLOG2E * gg);
                const float ig = (eg - 1.0f) * __builtin_amdgcn_rcpf((1.0f + ei) * (1.0f + eg)); // sig(gi)*tanh(gg)
                const float ff = __builtin_amdgcn_rcpf(1.0f + __builtin_amdgcn_exp2f(-LOG2E * gf));
                const float c  = ff * cs[q][r] + ig;
                cs[q][r] = c;
                const float eo = __builtin_amdgcn_exp2f(-LOG2E * go);
                const float ec = __builtin_amdgcn_exp2f( TLOG2E * c);
                pk.h[r] = (__bf16)((ec - 1.0f) * __builtin_amdgcn_rcpf((1.0f + eo) * (1.0f + ec))); // sig(go)*tanh(c)
            }
            const int off = wbuf + ln * stride + ((32*(wv + 4*q) + 8*lhi) ^ sw);
            *(uint2*)(lds + off) = pk.u2;
        }
    };

    __syncthreads();

    // ==== pipelined phases: phase t does L1(t-1) [t>0] then L0(t) [t<T]; ONE barrier each ====
    for (int t = 0; t <= T_SEQ; ++t) {
        const bool doL0 = (t < T_SEQ);
        const bool doL1 = (t > 0);
        const int pr  = t & 1;
        const int haR = (pr ^ 1) * HA_BUF;            // h_a(t-1) | x(t) | 1
        const int haW = pr * HA_BUF;                  // h_a(t) dest
        const int hbR = HB_BASE + pr * HB_BUF;        // h_b(t-2)
        const int hbW = HB_BASE + (pr ^ 1) * HB_BUF;  // h_b(t-1) dest

        // prefetch x(t+1) — latency hides under this phase's compute
        float xpre = 0.0f;
        if (doL0) {
            const int b = tid >> 4, i = tid & 15;
            if (i < IN_DIM) {
                int tt = t + 1; if (tt >= T_SEQ) tt = T_SEQ - 1;
                xpre = x[((size_t)(bs0 + b) * T_SEQ + tt) * IN_DIM + i];
            }
        }

        // B-fragments (frA shared by L1 input-projection and L0 recurrence)
        bf16x8 frA[4];
        {
            const int rb = haR + ln * HA_STRIDE;
            #pragma unroll
            for (int kk = 0; kk < 4; ++kk)
                frA[kk] = *(const bf16x8*)(lds + rb + ((kk*64 + lhi*16) ^ sw));
        }

        // ================= L1(t-1): g1 = [Wih1|Whh1]·[h_a(t-1); h_b(t-2)] + b1 =================
        if (doL1) {
            bf16x8 frB[4];
            {
                const int rb = hbR + ln * HB_STRIDE;
                #pragma unroll
                for (int kk = 0; kk < 4; ++kk)
                    frB[kk] = *(const bf16x8*)(lds + rb + ((kk*64 + lhi*16) ^ sw));
            }
            f32x4 acc1[4][2];
            #pragma unroll
            for (int g = 0; g < 4; ++g)
                #pragma unroll
                for (int q = 0; q < 2; ++q)
                    acc1[g][q] = *(const f32x4*)(lds + xbb + ((g*2 + q) << 6));
            #pragma unroll
            for (int kk = 0; kk < 4; ++kk)
                #pragma unroll
                for (int g = 0; g < 4; ++g)
                    #pragma unroll
                    for (int q = 0; q < 2; ++q)
                        acc1[g][q] = __builtin_amdgcn_mfma_f32_16x16x32_bf16(wA1[g][q][kk], frA[kk], acc1[g][q], 0, 0, 0);
            #pragma unroll
            for (int kk = 0; kk < 4; ++kk)
                #pragma unroll
                for (int g = 0; g < 4; ++g)
                    #pragma unroll
                    for (int q = 0; q < 2; ++q)
                        acc1[g][q] = __builtin_amdgcn_mfma_f32_16x16x32_bf16(wA1[g][q][4+kk], frB[kk], acc1[g][q], 0, 0, 0);
            nlw(acc1, cB, hbW, HB_STRIDE);
        }

        // ================= L0(t): g0 = Whh0·h_a(t-1) + [Wih0|b0]·[x(t);1] =================
        if (doL0) {
            f32x4 acc0[4][2];
            #pragma unroll
            for (int g = 0; g < 4; ++g)
                #pragma unroll
                for (int q = 0; q < 2; ++q)
                    acc0[g][q] = f32x4{0.f,0.f,0.f,0.f};
            #pragma unroll
            for (int kk = 0; kk < 4; ++kk)
                #pragma unroll
                for (int g = 0; g < 4; ++g)
                    #pragma unroll
                    for (int q = 0; q < 2; ++q)
                        acc0[g][q] = __builtin_amdgcn_mfma_f32_16x16x32_bf16(wA0[g][q][kk], frA[kk], acc0[g][q], 0, 0, 0);
            // x-augmented column: B-frag from hA cols 128..159, A-frags JIT from XA (masked)
            {
                const bf16x8 frA4 = *(const bf16x8*)(lds + haR + ln * HA_STRIDE + ((256 + lhi*16) ^ sw));
                #pragma unroll
                for (int g = 0; g < 4; ++g)
                    #pragma unroll
                    for (int q = 0; q < 2; ++q) {
                        const bf16x8 xw = *(const bf16x8*)(lds + xslot + (((g*2 + q) << 10) & xmask));
                        acc0[g][q] = __builtin_amdgcn_mfma_f32_16x16x32_bf16(xw, frA4, acc0[g][q], 0, 0, 0);
                    }
            }
            nlw(acc0, cA, haW, HA_STRIDE);
            // stash x(t+1) into the buffer written this phase (read next phase)
            const int b = tid >> 4, i = tid & 15;
            if (i < IN_DIM) {
                const int off = haW + b * HA_STRIDE + ((2*(128+i)) ^ ((b & 7) << 4));
                *(uint16_t*)(lds + off) = f2bf(xpre);
            }
        }
        __syncthreads();
    }

    // ---- epilogue: out = h_b(T-1) @ Wfc^T + bfc ; final h_b is in hB parity 1 ----
    if (tid < 64) {
        const int b = tid >> 2, c = tid & 3;
        float s = bfc[c];
        const float* wf = Wfc + (size_t)c * HID;
        const int rowoff = HB_BASE + HB_BUF + b * HB_STRIDE;
        const int swb = (b & 7) << 4;
        #pragma unroll 8
        for (int k = 0; k < HID; ++k) {
            const uint16_t hb = *(const uint16_t*)(lds + rowoff + ((2*k) ^ swb));
            s += bf2f(hb) * wf[k];
        }
        out[(size_t)(bs0 + b) * 4 + c] = s;
    }
}

extern "C" void kernel_launch(void* const* d_in, const int* in_sizes, int n_in,
                              void* d_out, int out_size, void* d_ws, size_t ws_size,
                              hipStream_t stream) {
    const float* x    = (const float*)d_in[0];
    const float* Wih0 = (const float*)d_in[1];
    const float* Whh0 = (const float*)d_in[2];
    const float* bih0 = (const float*)d_in[3];
    const float* bhh0 = (const float*)d_in[4];
    const float* Wih1 = (const float*)d_in[5];
    const float* Whh1 = (const float*)d_in[6];
    const float* bih1 = (const float*)d_in[7];
    const float* bhh1 = (const float*)d_in[8];
    const float* Wfc  = (const float*)d_in[9];
    const float* bfc  = (const float*)d_in[10];
    (void)in_sizes; (void)n_in; (void)d_ws; (void)ws_size; (void)out_size;

    hipLaunchKernelGGL(lstm2_kernel, dim3(NBLK), dim3(NTHR), 0, stream,
                       x, Wih0, Whh0, bih0, bhh0, Wih1, Whh1, bih1, bhh1, Wfc, bfc,
                       (float*)d_out);
}

// Round 4
// 3643.893 us; speedup vs baseline: 1.5521x; 1.4546x over previous
//
#include <hip/hip_runtime.h>
#include <hip/hip_bf16.h>
#include <stdint.h>

// ---------------- problem constants ----------------
#define T_SEQ  2000
#define IN_DIM 13
#define HID    128
#define NB     16           // batch rows per block
#define NBLK   32           // 512 / NB
#define NTHR   512          // 8 waves -> 2 waves/SIMD (TLP) ; 256-VGPR cap per wave

// ---------------- LDS geometry ----------------
// hA: [2 parity][16 rows][192 cols bf16]; row = [h_a(0..127) | x(128..140) | 1.0(141) | 0]
// hB: [2 parity][16 rows][128 cols bf16]
// XB: L1 bias f32x4 per (wv,g,lhi) — uniform-address broadcast reads
// XZ: 16B permanent zeros (masked xaug reads for lanes lhi>=2)
// XA: L0 x-augmented weight frags [wv][g][ln][lhi<2]
#define HA_STRIDE 384
#define HA_BUF    (NB * HA_STRIDE)           // 6144
#define HB_STRIDE 256
#define HB_BUF    (NB * HB_STRIDE)           // 4096
#define HB_BASE   (2 * HA_BUF)               // 12288
#define XB_BASE   (HB_BASE + 2 * HB_BUF)     // 20480 (8*4*4*16 = 2048 B)
#define XZ_OFF    (XB_BASE + 2048)           // 22528
#define XA_BASE   24576                      // 8*4 slots * 1KB = 32KB
#define LDS_BYTES (XA_BASE + 32768)          // 57344
#define ZERO_W    ((XZ_OFF + 16) / 4)

typedef __bf16 bf16x8 __attribute__((ext_vector_type(8)));
typedef float  f32x4  __attribute__((ext_vector_type(4)));

__device__ __forceinline__ uint16_t f2bf(float f) {
    union { float f; uint32_t u; } v; v.f = f;
    return (uint16_t)((v.u + 0x7FFFu + ((v.u >> 16) & 1u)) >> 16);  // RNE
}
__device__ __forceinline__ float bf2f(uint16_t b) {
    union { uint32_t u; float f; } v; v.u = ((uint32_t)b) << 16; return v.f;
}

#define LOG2E 1.44269504088896340736f
#define TLOG2E 2.88539008177792681472f

__global__ __launch_bounds__(NTHR, 2)
void lstm2_kernel(const float* __restrict__ x,
                  const float* __restrict__ Wih0, const float* __restrict__ Whh0,
                  const float* __restrict__ bih0, const float* __restrict__ bhh0,
                  const float* __restrict__ Wih1, const float* __restrict__ Whh1,
                  const float* __restrict__ bih1, const float* __restrict__ bhh1,
                  const float* __restrict__ Wfc,  const float* __restrict__ bfc,
                  float* __restrict__ out)
{
    __shared__ alignas(16) unsigned char lds[LDS_BYTES];

    const int tid  = threadIdx.x;
    const int lane = tid & 63;
    const int wv   = tid >> 6;     // wave 0..7
    const int ln   = lane & 15;    // batch col (B-frag) / weight row-in-tile (A-frag)
    const int lhi  = lane >> 4;    // k-group 0..3
    const int bs0  = blockIdx.x * NB;

    // ---- zero the dynamic LDS region ----
    for (int i = tid; i < ZERO_W; i += NTHR) ((uint32_t*)lds)[i] = 0u;
    __syncthreads();

    // constant 1.0 at col 141 (bias slot of the x-augmented block), both parities
    if (tid < 2*NB) {
        int p = tid >> 4, n = tid & 15;
        int off = p*HA_BUF + n*HA_STRIDE + (282 ^ ((n & 7) << 4));
        *(uint16_t*)(lds + off) = 0x3F80u;
    }
    // x~(t=0) into hA parity 1 (phase 0 reads hA[1])
    if (tid < 256) {
        int b = tid >> 4, i = tid & 15;
        if (i < IN_DIM) {
            float xv = x[((size_t)(bs0 + b) * T_SEQ + 0) * IN_DIM + i];
            int off = HA_BUF + b*HA_STRIDE + ((2*(128 + i)) ^ ((b & 7) << 4));
            *(uint16_t*)(lds + off) = f2bf(xv);
        }
    }
    // L1 bias into XB: f32x4 per (wv,g,lhi), written by ln==0 lanes
    if (ln == 0) {
        #pragma unroll
        for (int g = 0; g < 4; ++g) {
            const int g0 = (8*g + wv) * 16 + lhi*4;
            f32x4 bv;
            #pragma unroll
            for (int r = 0; r < 4; ++r) bv[r] = bih1[g0+r] + bhh1[g0+r];
            *(f32x4*)(lds + XB_BASE + (((wv*4 + g)*4 + lhi) << 4)) = bv;
        }
    }
    // L0 x-augmented weight frags into XA ([Wih0 | bias0 | 0...], bf16)
    {
        const int myoff = (ln*64 + lhi*16) ^ ((ln & 7) << 4);
        #pragma unroll
        for (int g = 0; g < 4; ++g) {
            const int grow = (8*g + wv) * 16 + ln;
            union { __bf16 h[8]; uint4 u4; } fr;
            const int c0 = lhi * 8;
            #pragma unroll
            for (int j = 0; j < 8; ++j) {
                const int c = c0 + j;
                float v = 0.0f;
                if (c < IN_DIM)       v = Wih0[(size_t)grow * IN_DIM + c];
                else if (c == IN_DIM) v = bih0[grow] + bhh0[grow];
                fr.h[j] = (__bf16)v;
            }
            *(uint4*)(lds + XA_BASE + ((wv*4 + g) << 10) + myoff) = fr.u4;
        }
    }

    // ---- register-resident weight fragments (A-operand: gates-as-M) ----
    // wave wv owns gate-tile (8g+wv) per gate g -> hidden units [16wv,16wv+16)
    bf16x8 wA0[4][4];   // L0: Whh0
    bf16x8 wA1[4][8];   // L1: kk 0..3 = Wih1, kk 4..7 = Whh1
    #pragma unroll
    for (int g = 0; g < 4; ++g) {
        const int grow = (8*g + wv) * 16 + ln;
        #pragma unroll
        for (int kk = 0; kk < 4; ++kk) {
            const float* s = Whh0 + (size_t)grow * HID + kk*32 + lhi*8;
            #pragma unroll
            for (int j = 0; j < 8; ++j) wA0[g][kk][j] = (__bf16)s[j];
        }
        #pragma unroll
        for (int kk = 0; kk < 4; ++kk) {
            const float* s = Wih1 + (size_t)grow * HID + kk*32 + lhi*8;
            #pragma unroll
            for (int j = 0; j < 8; ++j) wA1[g][kk][j] = (__bf16)s[j];
        }
        #pragma unroll
        for (int kk = 0; kk < 4; ++kk) {
            const float* s = Whh1 + (size_t)grow * HID + kk*32 + lhi*8;
            #pragma unroll
            for (int j = 0; j < 8; ++j) wA1[g][4+kk][j] = (__bf16)s[j];
        }
    }

    f32x4 cA = {0.f,0.f,0.f,0.f};
    f32x4 cB = {0.f,0.f,0.f,0.f};
    const int sw = (ln & 7) << 4;      // read/write swizzle for this lane's row

    // loop-invariant addresses
    const int xslot = (lhi < 2) ? (XA_BASE + (wv << 12) + ((ln*64 + lhi*16) ^ sw))
                                : XZ_OFF;
    const int xmask = (lhi < 2) ? ~0 : 0;
    const int xbb   = XB_BASE + ((wv*16 + lhi) << 4);   // + g*64

    // nonlinearity + pack + LDS write for one layer
    auto nlw = [&](f32x4 (&ac)[4], f32x4 &cs, int wbuf, int stride) {
        union { __bf16 h[4]; uint2 u2; } pk;
        #pragma unroll
        for (int r = 0; r < 4; ++r) {
            const float gi = ac[0][r], gf = ac[1][r], gg = ac[2][r], go = ac[3][r];
            const float ei = __builtin_amdgcn_exp2f(-LOG2E * gi);
            const float eg = __builtin_amdgcn_exp2f( TLOG2E * gg);
            const float ig = (eg - 1.0f) * __builtin_amdgcn_rcpf((1.0f + ei) * (1.0f + eg)); // sig(gi)*tanh(gg)
            const float ff = __builtin_amdgcn_rcpf(1.0f + __builtin_amdgcn_exp2f(-LOG2E * gf));
            const float c  = ff * cs[r] + ig;
            cs[r] = c;
            const float eo = __builtin_amdgcn_exp2f(-LOG2E * go);
            const float ec = __builtin_amdgcn_exp2f( TLOG2E * c);
            pk.h[r] = (__bf16)((ec - 1.0f) * __builtin_amdgcn_rcpf((1.0f + eo) * (1.0f + ec))); // sig(go)*tanh(c)
        }
        const int off = wbuf + ln * stride + ((32*wv + 8*lhi) ^ sw);
        *(uint2*)(lds + off) = pk.u2;
    };

    // one pipelined phase: L1(t-1) then L0(t), single barrier
    auto phase = [&](bool doL1, bool doL0, int t) {
        const int pr  = t & 1;
        const int haR = (pr ^ 1) * HA_BUF;            // h_a(t-1) | x(t) | 1
        const int haW = pr * HA_BUF;                  // h_a(t) dest
        const int hbR = HB_BASE + pr * HB_BUF;        // h_b(t-2)
        const int hbW = HB_BASE + (pr ^ 1) * HB_BUF;  // h_b(t-1) dest

        // prefetch x(t+1)
        float xpre = 0.0f;
        if (doL0 && tid < 256) {
            const int b = tid >> 4, i = tid & 15;
            if (i < IN_DIM) {
                int tt = t + 1; if (tt >= T_SEQ) tt = T_SEQ - 1;
                xpre = x[((size_t)(bs0 + b) * T_SEQ + tt) * IN_DIM + i];
            }
        }

        // shared B-fragments: h_a(t-1)
        bf16x8 frA[4];
        {
            const int rb = haR + ln * HA_STRIDE;
            #pragma unroll
            for (int kk = 0; kk < 4; ++kk)
                frA[kk] = *(const bf16x8*)(lds + rb + ((kk*64 + lhi*16) ^ sw));
        }

        // ---- L1(t-1): g1 = Wih1·h_a(t-1) + Whh1·h_b(t-2) + b1 ----
        if (doL1) {
            bf16x8 frB[4];
            {
                const int rb = hbR + ln * HB_STRIDE;
                #pragma unroll
                for (int kk = 0; kk < 4; ++kk)
                    frB[kk] = *(const bf16x8*)(lds + rb + ((kk*64 + lhi*16) ^ sw));
            }
            f32x4 acc1[4];
            #pragma unroll
            for (int g = 0; g < 4; ++g)
                acc1[g] = *(const f32x4*)(lds + xbb + (g << 6));
            #pragma unroll
            for (int kk = 0; kk < 4; ++kk)
                #pragma unroll
                for (int g = 0; g < 4; ++g)
                    acc1[g] = __builtin_amdgcn_mfma_f32_16x16x32_bf16(wA1[g][kk], frA[kk], acc1[g], 0, 0, 0);
            #pragma unroll
            for (int kk = 0; kk < 4; ++kk)
                #pragma unroll
                for (int g = 0; g < 4; ++g)
                    acc1[g] = __builtin_amdgcn_mfma_f32_16x16x32_bf16(wA1[g][4+kk], frB[kk], acc1[g], 0, 0, 0);
            nlw(acc1, cB, hbW, HB_STRIDE);
        }

        // ---- L0(t): g0 = Whh0·h_a(t-1) + [Wih0|b0]·[x(t);1] ----
        if (doL0) {
            f32x4 acc0[4];
            #pragma unroll
            for (int g = 0; g < 4; ++g) acc0[g] = f32x4{0.f,0.f,0.f,0.f};
            #pragma unroll
            for (int kk = 0; kk < 4; ++kk)
                #pragma unroll
                for (int g = 0; g < 4; ++g)
                    acc0[g] = __builtin_amdgcn_mfma_f32_16x16x32_bf16(wA0[g][kk], frA[kk], acc0[g], 0, 0, 0);
            {
                const bf16x8 frA4 = *(const bf16x8*)(lds + haR + ln * HA_STRIDE + ((256 + lhi*16) ^ sw));
                #pragma unroll
                for (int g = 0; g < 4; ++g) {
                    const bf16x8 xw = *(const bf16x8*)(lds + xslot + ((g << 10) & xmask));
                    acc0[g] = __builtin_amdgcn_mfma_f32_16x16x32_bf16(xw, frA4, acc0[g], 0, 0, 0);
                }
            }
            nlw(acc0, cA, haW, HA_STRIDE);
            // stash x(t+1) into the buffer written this phase (read next phase)
            if (tid < 256) {
                const int b = tid >> 4, i = tid & 15;
                if (i < IN_DIM) {
                    const int off = haW + b * HA_STRIDE + ((2*(128+i)) ^ ((b & 7) << 4));
                    *(uint16_t*)(lds + off) = f2bf(xpre);
                }
            }
        }
        __syncthreads();
    };

    __syncthreads();

    phase(false, true, 0);                       // prologue: L0(0) only
    for (int t = 1; t < T_SEQ; ++t)              // steady state: branch-free body
        phase(true, true, t);
    phase(true, false, T_SEQ);                   // epilogue phase: L1(T-1) only

    // ---- epilogue: out = h_b(T-1) @ Wfc^T + bfc ; final h_b is in hB parity 1 ----
    if (tid < 64) {
        const int b = tid >> 2, c = tid & 3;
        float s = bfc[c];
        const float* wf = Wfc + (size_t)c * HID;
        const int rowoff = HB_BASE + HB_BUF + b * HB_STRIDE;
        const int swb = (b & 7) << 4;
        #pragma unroll 8
        for (int k = 0; k < HID; ++k) {
            const uint16_t hb = *(const uint16_t*)(lds + rowoff + ((2*k) ^ swb));
            s += bf2f(hb) * wf[k];
        }
        out[(size_t)(bs0 + b) * 4 + c] = s;
    }
}

extern "C" void kernel_launch(void* const* d_in, const int* in_sizes, int n_in,
                              void* d_out, int out_size, void* d_ws, size_t ws_size,
                              hipStream_t stream) {
    const float* x    = (const float*)d_in[0];
    const float* Wih0 = (const float*)d_in[1];
    const float* Whh0 = (const float*)d_in[2];
    const float* bih0 = (const float*)d_in[3];
    const float* bhh0 = (const float*)d_in[4];
    const float* Wih1 = (const float*)d_in[5];
    const float* Whh1 = (const float*)d_in[6];
    const float* bih1 = (const float*)d_in[7];
    const float* bhh1 = (const float*)d_in[8];
    const float* Wfc  = (const float*)d_in[9];
    const float* bfc  = (const float*)d_in[10];
    (void)in_sizes; (void)n_in; (void)d_ws; (void)ws_size; (void)out_size;

    hipLaunchKernelGGL(lstm2_kernel, dim3(NBLK), dim3(NTHR), 0, stream,
                       x, Wih0, Whh0, bih0, bhh0, Wih1, Whh1, bih1, bhh1, Wfc, bfc,
                       (float*)d_out);
}

// Round 5
// 3603.534 us; speedup vs baseline: 1.5694x; 1.0112x over previous
//
#include <hip/hip_runtime.h>
#include <hip/hip_bf16.h>
#include <stdint.h>

// ---------------- problem constants ----------------
#define T_SEQ  2000
#define IN_DIM 13
#define HID    128
#define NB     16           // batch rows per block
#define NBLK   32           // 512 / NB
#define NTHR   512          // 8 waves -> 2 waves/SIMD (TLP)

// ---------------- LDS geometry ----------------
// hA: [2 parity][16 rows][192 cols bf16]; row = [h_a(0..127) | x(128..140) | 1.0(141) | 0]
// hB: [2 parity][16 rows][128 cols bf16]
// XB: L1 bias f32x4 per (wv,g,lhi) — uniform-address broadcast reads
// XZ: 16B permanent zeros (masked xaug reads for lanes lhi>=2)
// XA: L0 x-augmented weight frags [wv][g][ln][lhi<2]
#define HA_STRIDE 384
#define HA_BUF    (NB * HA_STRIDE)           // 6144
#define HB_STRIDE 256
#define HB_BUF    (NB * HB_STRIDE)           // 4096
#define HB_BASE   (2 * HA_BUF)               // 12288
#define XB_BASE   (HB_BASE + 2 * HB_BUF)     // 20480
#define XZ_OFF    (XB_BASE + 2048)           // 22528
#define XA_BASE   24576                      // 8*4 slots * 1KB = 32KB
#define LDS_BYTES (XA_BASE + 32768)          // 57344
#define ZERO_W    ((XZ_OFF + 16) / 4)

typedef __bf16 bf16x8 __attribute__((ext_vector_type(8)));
typedef float  f32x4  __attribute__((ext_vector_type(4)));

__device__ __forceinline__ uint16_t f2bf(float f) {
    union { float f; uint32_t u; } v; v.f = f;
    return (uint16_t)((v.u + 0x7FFFu + ((v.u >> 16) & 1u)) >> 16);  // RNE
}
__device__ __forceinline__ float bf2f(uint16_t b) {
    union { uint32_t u; float f; } v; v.u = ((uint32_t)b) << 16; return v.f;
}

#define LOG2E 1.44269504088896340736f
#define TLOG2E 2.88539008177792681472f

// raw barrier: LDS-drain only (skip the vmcnt(0) drain __syncthreads would emit;
// the per-step x global-load's wait stays at its use site, off the barrier path)
__device__ __forceinline__ void lds_barrier() {
    asm volatile("s_waitcnt lgkmcnt(0)" ::: "memory");
    __builtin_amdgcn_sched_barrier(0);
    __builtin_amdgcn_s_barrier();
    __builtin_amdgcn_sched_barrier(0);
}

__global__ __launch_bounds__(NTHR, 2)
void lstm2_kernel(const float* __restrict__ x,
                  const float* __restrict__ Wih0, const float* __restrict__ Whh0,
                  const float* __restrict__ bih0, const float* __restrict__ bhh0,
                  const float* __restrict__ Wih1, const float* __restrict__ Whh1,
                  const float* __restrict__ bih1, const float* __restrict__ bhh1,
                  const float* __restrict__ Wfc,  const float* __restrict__ bfc,
                  float* __restrict__ out)
{
    __shared__ alignas(16) unsigned char lds[LDS_BYTES];

    const int tid  = threadIdx.x;
    const int lane = tid & 63;
    const int wv   = tid >> 6;     // wave 0..7
    const int ln   = lane & 15;    // batch col (B-frag) / weight row-in-tile (A-frag)
    const int lhi  = lane >> 4;    // k-group 0..3
    const int bs0  = blockIdx.x * NB;

    // ---- zero the dynamic LDS region ----
    for (int i = tid; i < ZERO_W; i += NTHR) ((uint32_t*)lds)[i] = 0u;
    __syncthreads();

    // constant 1.0 at col 141 (bias slot of the x-augmented block), both parities
    if (tid < 2*NB) {
        int p = tid >> 4, n = tid & 15;
        int off = p*HA_BUF + n*HA_STRIDE + (282 ^ ((n & 7) << 4));
        *(uint16_t*)(lds + off) = 0x3F80u;
    }
    // x~(t=0) into hA parity 1 (phase 0 reads hA[1])
    if (tid < 256) {
        int b = tid >> 4, i = tid & 15;
        if (i < IN_DIM) {
            float xv = x[((size_t)(bs0 + b) * T_SEQ + 0) * IN_DIM + i];
            int off = HA_BUF + b*HA_STRIDE + ((2*(128 + i)) ^ ((b & 7) << 4));
            *(uint16_t*)(lds + off) = f2bf(xv);
        }
    }
    // L1 bias into XB: f32x4 per (wv,g,lhi), written by ln==0 lanes
    if (ln == 0) {
        #pragma unroll
        for (int g = 0; g < 4; ++g) {
            const int g0 = (8*g + wv) * 16 + lhi*4;
            f32x4 bv;
            #pragma unroll
            for (int r = 0; r < 4; ++r) bv[r] = bih1[g0+r] + bhh1[g0+r];
            *(f32x4*)(lds + XB_BASE + (((wv*4 + g)*4 + lhi) << 4)) = bv;
        }
    }
    // L0 x-augmented weight frags into XA ([Wih0 | bias0 | 0...], bf16)
    {
        const int myoff = (ln*64 + lhi*16) ^ ((ln & 7) << 4);
        #pragma unroll
        for (int g = 0; g < 4; ++g) {
            const int grow = (8*g + wv) * 16 + ln;
            union { __bf16 h[8]; uint4 u4; } fr;
            const int c0 = lhi * 8;
            #pragma unroll
            for (int j = 0; j < 8; ++j) {
                const int c = c0 + j;
                float v = 0.0f;
                if (c < IN_DIM)       v = Wih0[(size_t)grow * IN_DIM + c];
                else if (c == IN_DIM) v = bih0[grow] + bhh0[grow];
                fr.h[j] = (__bf16)v;
            }
            *(uint4*)(lds + XA_BASE + ((wv*4 + g) << 10) + myoff) = fr.u4;
        }
    }

    // ---- register-resident weight fragments (A-operand: gates-as-M) ----
    // wave wv owns gate-tile (8g+wv) per gate g -> hidden units [16wv,16wv+16)
    bf16x8 wA0[4][4];   // L0: Whh0
    bf16x8 wA1[4][8];   // L1: kk 0..3 = Wih1, kk 4..7 = Whh1
    #pragma unroll
    for (int g = 0; g < 4; ++g) {
        const int grow = (8*g + wv) * 16 + ln;
        #pragma unroll
        for (int kk = 0; kk < 4; ++kk) {
            const float* s = Whh0 + (size_t)grow * HID + kk*32 + lhi*8;
            #pragma unroll
            for (int j = 0; j < 8; ++j) wA0[g][kk][j] = (__bf16)s[j];
        }
        #pragma unroll
        for (int kk = 0; kk < 4; ++kk) {
            const float* s = Wih1 + (size_t)grow * HID + kk*32 + lhi*8;
            #pragma unroll
            for (int j = 0; j < 8; ++j) wA1[g][kk][j] = (__bf16)s[j];
        }
        #pragma unroll
        for (int kk = 0; kk < 4; ++kk) {
            const float* s = Whh1 + (size_t)grow * HID + kk*32 + lhi*8;
            #pragma unroll
            for (int j = 0; j < 8; ++j) wA1[g][4+kk][j] = (__bf16)s[j];
        }
    }

    f32x4 cA = {0.f,0.f,0.f,0.f};
    f32x4 cB = {0.f,0.f,0.f,0.f};
    const int sw = (ln & 7) << 4;      // read/write swizzle for this lane's row

    // loop-invariant addresses
    const int xslot = (lhi < 2) ? (XA_BASE + (wv << 12) + ((ln*64 + lhi*16) ^ sw))
                                : XZ_OFF;
    const int xmask = (lhi < 2) ? ~0 : 0;
    const int xbb   = XB_BASE + ((wv*16 + lhi) << 4);   // + g*64

    // nonlinearity + pack + LDS write for one layer.
    // 7 trans/unit: c = (c*p2 + (eg-1)*p1) / (p1*p2)  [f-gate rcp fused into c-update]
    auto nlw = [&](f32x4 (&ac)[4], f32x4 &cs, int wbuf, int stride) {
        float h[4];
        #pragma unroll
        for (int r = 0; r < 4; ++r) {
            const float ei = __builtin_amdgcn_exp2f(-LOG2E  * ac[0][r]);
            const float ef = __builtin_amdgcn_exp2f(-LOG2E  * ac[1][r]);
            const float eg = __builtin_amdgcn_exp2f( TLOG2E * ac[2][r]);
            const float eo = __builtin_amdgcn_exp2f(-LOG2E  * ac[3][r]);
            const float p1 = 1.0f + ef;
            const float p2 = (1.0f + ei) * (1.0f + eg);
            const float num = fmaf(cs[r] , p2, (eg - 1.0f) * p1);
            const float c  = num * __builtin_amdgcn_rcpf(p1 * p2);
            cs[r] = c;
            const float ec = __builtin_amdgcn_exp2f(TLOG2E * c);
            h[r] = (ec - 1.0f) * __builtin_amdgcn_rcpf((1.0f + eo) * (1.0f + ec)); // sig(go)*tanh(c)
        }
        uint2 u2;
        asm("v_cvt_pk_bf16_f32 %0, %1, %2" : "=v"(u2.x) : "v"(h[0]), "v"(h[1]));
        asm("v_cvt_pk_bf16_f32 %0, %1, %2" : "=v"(u2.y) : "v"(h[2]), "v"(h[3]));
        const int off = wbuf + ln * stride + ((32*wv + 8*lhi) ^ sw);
        *(uint2*)(lds + off) = u2;
    };

    // one pipelined phase: L1(t-1) then L0(t), single raw barrier
    auto phase = [&](bool doL1, bool doL0, int t) {
        const int pr  = t & 1;
        const int haR = (pr ^ 1) * HA_BUF;            // h_a(t-1) | x(t) | 1
        const int haW = pr * HA_BUF;                  // h_a(t) dest
        const int hbR = HB_BASE + pr * HB_BUF;        // h_b(t-2)
        const int hbW = HB_BASE + (pr ^ 1) * HB_BUF;  // h_b(t-1) dest

        // prefetch x(t+1); vmcnt wait lands at the stash, not the barrier
        float xpre = 0.0f;
        if (doL0 && tid < 256) {
            const int b = tid >> 4, i = tid & 15;
            if (i < IN_DIM) {
                int tt = t + 1; if (tt >= T_SEQ) tt = T_SEQ - 1;
                xpre = x[((size_t)(bs0 + b) * T_SEQ + tt) * IN_DIM + i];
            }
        }

        // shared B-fragments: h_a(t-1)
        bf16x8 frA[4];
        {
            const int rb = haR + ln * HA_STRIDE;
            #pragma unroll
            for (int kk = 0; kk < 4; ++kk)
                frA[kk] = *(const bf16x8*)(lds + rb + ((kk*64 + lhi*16) ^ sw));
        }

        // ---- L1(t-1): g1 = Wih1·h_a(t-1) + Whh1·h_b(t-2) + b1 ----
        if (doL1) {
            bf16x8 frB[4];
            {
                const int rb = hbR + ln * HB_STRIDE;
                #pragma unroll
                for (int kk = 0; kk < 4; ++kk)
                    frB[kk] = *(const bf16x8*)(lds + rb + ((kk*64 + lhi*16) ^ sw));
            }
            f32x4 acc1[4];
            #pragma unroll
            for (int g = 0; g < 4; ++g)
                acc1[g] = *(const f32x4*)(lds + xbb + (g << 6));
            #pragma unroll
            for (int kk = 0; kk < 4; ++kk)
                #pragma unroll
                for (int g = 0; g < 4; ++g)
                    acc1[g] = __builtin_amdgcn_mfma_f32_16x16x32_bf16(wA1[g][kk], frA[kk], acc1[g], 0, 0, 0);
            #pragma unroll
            for (int kk = 0; kk < 4; ++kk)
                #pragma unroll
                for (int g = 0; g < 4; ++g)
                    acc1[g] = __builtin_amdgcn_mfma_f32_16x16x32_bf16(wA1[g][4+kk], frB[kk], acc1[g], 0, 0, 0);
            nlw(acc1, cB, hbW, HB_STRIDE);
        }

        // ---- L0(t): g0 = Whh0·h_a(t-1) + [Wih0|b0]·[x(t);1] ----
        if (doL0) {
            f32x4 acc0[4];
            #pragma unroll
            for (int g = 0; g < 4; ++g) acc0[g] = f32x4{0.f,0.f,0.f,0.f};
            #pragma unroll
            for (int kk = 0; kk < 4; ++kk)
                #pragma unroll
                for (int g = 0; g < 4; ++g)
                    acc0[g] = __builtin_amdgcn_mfma_f32_16x16x32_bf16(wA0[g][kk], frA[kk], acc0[g], 0, 0, 0);
            {
                const bf16x8 frA4 = *(const bf16x8*)(lds + haR + ln * HA_STRIDE + ((256 + lhi*16) ^ sw));
                #pragma unroll
                for (int g = 0; g < 4; ++g) {
                    const bf16x8 xw = *(const bf16x8*)(lds + xslot + ((g << 10) & xmask));
                    acc0[g] = __builtin_amdgcn_mfma_f32_16x16x32_bf16(xw, frA4, acc0[g], 0, 0, 0);
                }
            }
            nlw(acc0, cA, haW, HA_STRIDE);
            // stash x(t+1) into the buffer written this phase (read next phase)
            if (tid < 256) {
                const int b = tid >> 4, i = tid & 15;
                if (i < IN_DIM) {
                    const int off = haW + b * HA_STRIDE + ((2*(128+i)) ^ ((b & 7) << 4));
                    *(uint16_t*)(lds + off) = f2bf(xpre);
                }
            }
        }
        lds_barrier();
    };

    __syncthreads();

    phase(false, true, 0);                       // prologue: L0(0) only
    #pragma unroll 2
    for (int t = 1; t < T_SEQ; ++t)              // steady state: branch-free body
        phase(true, true, t);
    phase(true, false, T_SEQ);                   // epilogue phase: L1(T-1) only

    // ---- epilogue: out = h_b(T-1) @ Wfc^T + bfc ; final h_b is in hB parity 1 ----
    if (tid < 64) {
        const int b = tid >> 2, c = tid & 3;
        float s = bfc[c];
        const float* wf = Wfc + (size_t)c * HID;
        const int rowoff = HB_BASE + HB_BUF + b * HB_STRIDE;
        const int swb = (b & 7) << 4;
        #pragma unroll 8
        for (int k = 0; k < HID; ++k) {
            const uint16_t hb = *(const uint16_t*)(lds + rowoff + ((2*k) ^ swb));
            s += bf2f(hb) * wf[k];
        }
        out[(size_t)(bs0 + b) * 4 + c] = s;
    }
}

extern "C" void kernel_launch(void* const* d_in, const int* in_sizes, int n_in,
                              void* d_out, int out_size, void* d_ws, size_t ws_size,
                              hipStream_t stream) {
    const float* x    = (const float*)d_in[0];
    const float* Wih0 = (const float*)d_in[1];
    const float* Whh0 = (const float*)d_in[2];
    const float* bih0 = (const float*)d_in[3];
    const float* bhh0 = (const float*)d_in[4];
    const float* Wih1 = (const float*)d_in[5];
    const float* Whh1 = (const float*)d_in[6];
    const float* bih1 = (const float*)d_in[7];
    const float* bhh1 = (const float*)d_in[8];
    const float* Wfc  = (const float*)d_in[9];
    const float* bfc  = (const float*)d_in[10];
    (void)in_sizes; (void)n_in; (void)d_ws; (void)ws_size; (void)out_size;

    hipLaunchKernelGGL(lstm2_kernel, dim3(NBLK), dim3(NTHR), 0, stream,
                       x, Wih0, Whh0, bih0, bhh0, Wih1, Whh1, bih1, bhh1, Wfc, bfc,
                       (float*)d_out);
}